// Round 1
// baseline (254.071 us; speedup 1.0000x reference)
//
#include <hip/hip_runtime.h>

// BoundaryKDV7: per-pixel channel-softmax KL(T||S), masked by class-boundary
// pixels, binned per (batch, class 1..13), normalized, summed to scalar.
//
// Shapes: preds_S/preds_T [8,14,512,512] f32, gt [8,1,512,512] i32, out: 1 f32.

#define CC 14
#define KB 13          // boundary classes 1..13
#define BB 8
#define HH 512
#define WW 512
#define PP (HH * WW)   // 262144 pixels per image
#define PIX_PER_BLOCK 1024
#define BLOCKS_PER_IMG (PP / PIX_PER_BLOCK)   // 256

// ws layout (floats): [0 .. 103] kl_sum[b][k-1], [104 .. 207] n[b][k-1]
#define NBINS (BB * KB)

__device__ __forceinline__ float4 f4max(float4 a, float4 b) {
    return make_float4(fmaxf(a.x, b.x), fmaxf(a.y, b.y), fmaxf(a.z, b.z), fmaxf(a.w, b.w));
}
__device__ __forceinline__ float4 f4sub(float4 a, float4 b) {
    return make_float4(a.x - b.x, a.y - b.y, a.z - b.z, a.w - b.w);
}
__device__ __forceinline__ float4 f4exp(float4 a) {
    return make_float4(__expf(a.x), __expf(a.y), __expf(a.z), __expf(a.w));
}

__global__ void zero_ws_kernel(float* __restrict__ ws) {
    int i = threadIdx.x;
    if (i < 2 * NBINS) ws[i] = 0.0f;
}

__global__ __launch_bounds__(256) void boundary_kl_kernel(
        const float* __restrict__ S, const float* __restrict__ T,
        const int* __restrict__ gt, float* __restrict__ ws) {
    const int tid = threadIdx.x;
    const int b   = blockIdx.x / BLOCKS_PER_IMG;
    const int p0  = (blockIdx.x % BLOCKS_PER_IMG) * PIX_PER_BLOCK + tid * 4;

    __shared__ float s_kl[KB + 1];
    __shared__ float s_n[KB + 1];
    if (tid <= KB) { s_kl[tid] = 0.0f; s_n[tid] = 0.0f; }
    __syncthreads();

    const float* Sb = S + (size_t)b * CC * PP + p0;
    const float* Tb = T + (size_t)b * CC * PP + p0;
    const int*  gtb = gt + (size_t)b * PP;

    // ---- load all 14 channels x 4 pixels for both tensors (registers) ----
    float4 xs[CC], xt[CC];
#pragma unroll
    for (int c = 0; c < CC; ++c) {
        xs[c] = *(const float4*)(Sb + (size_t)c * PP);
        xt[c] = *(const float4*)(Tb + (size_t)c * PP);
    }

    // ---- per-pixel (vector of 4) log-softmax KL ----
    float4 mS = xs[0], mT = xt[0];
#pragma unroll
    for (int c = 1; c < CC; ++c) { mS = f4max(mS, xs[c]); mT = f4max(mT, xt[c]); }

    float4 zS = make_float4(0.f, 0.f, 0.f, 0.f);
    float4 zT = make_float4(0.f, 0.f, 0.f, 0.f);
    float4 A  = make_float4(0.f, 0.f, 0.f, 0.f);
#pragma unroll
    for (int c = 0; c < CC; ++c) {
        float4 eS = f4exp(f4sub(xs[c], mS));
        float4 eT = f4exp(f4sub(xt[c], mT));
        zS.x += eS.x; zS.y += eS.y; zS.z += eS.z; zS.w += eS.w;
        zT.x += eT.x; zT.y += eT.y; zT.z += eT.z; zT.w += eT.w;
        float4 d = f4sub(xt[c], xs[c]);
        A.x += eT.x * d.x; A.y += eT.y * d.y; A.z += eT.z * d.z; A.w += eT.w * d.w;
    }
    // kl = A/ZT + (mS + log ZS) - (mT + log ZT)
    float kl[4];
    kl[0] = A.x / zT.x + (mS.x + __logf(zS.x)) - (mT.x + __logf(zT.x));
    kl[1] = A.y / zT.y + (mS.y + __logf(zS.y)) - (mT.y + __logf(zT.y));
    kl[2] = A.z / zT.z + (mS.z + __logf(zS.z)) - (mT.z + __logf(zT.z));
    kl[3] = A.w / zT.w + (mS.w + __logf(zS.w)) - (mT.w + __logf(zT.w));

    // ---- boundary test (cross erosion, zero border => border pixels are boundary) ----
    const int h = p0 >> 9;        // p0 / 512
    const int w = p0 & (WW - 1);  // p0 % 512 (multiple of 4)
    int4 g = *(const int4*)(gtb + p0);
    int4 gu = make_int4(-1, -1, -1, -1);
    int4 gd = make_int4(-1, -1, -1, -1);
    if (h > 0)      gu = *(const int4*)(gtb + p0 - WW);
    if (h < HH - 1) gd = *(const int4*)(gtb + p0 + WW);
    const int gl = (w > 0)       ? gtb[p0 - 1] : -1;
    const int gr = (w + 4 < WW)  ? gtb[p0 + 4] : -1;

    const int gc[4]  = {g.x, g.y, g.z, g.w};
    const int gup[4] = {gu.x, gu.y, gu.z, gu.w};
    const int gdn[4] = {gd.x, gd.y, gd.z, gd.w};
    const int glf[4] = {gl, g.x, g.y, g.z};
    const int grt[4] = {g.y, g.z, g.w, gr};

#pragma unroll
    for (int j = 0; j < 4; ++j) {
        const int k = gc[j];
        const bool eroded = (glf[j] == k) & (grt[j] == k) & (gup[j] == k) & (gdn[j] == k);
        if (k >= 1 && !eroded) {
            atomicAdd(&s_kl[k], kl[j]);
            atomicAdd(&s_n[k], 1.0f);
        }
    }
    __syncthreads();

    if (tid >= 1 && tid <= KB) {
        atomicAdd(&ws[b * KB + (tid - 1)], s_kl[tid]);
        atomicAdd(&ws[NBINS + b * KB + (tid - 1)], s_n[tid]);
    }
}

__global__ void finalize_kernel(const float* __restrict__ ws,
                                const int* __restrict__ gt,
                                float* __restrict__ out) {
    __shared__ float partial[128];
    const int tid = threadIdx.x;  // 128 threads
    float t = 0.0f;
    if (tid < NBINS) {
        const int b = tid / KB;
        const int k = (tid % KB) + 1;
        const float kl = ws[tid];
        const float n  = ws[NBINS + tid];
        // Pixel p=0 of image b is a corner -> boundary iff gt[b,0,0] >= 1.
        // valid = exists boundary pixel with flat index > 0.
        const int k0 = gt[(size_t)b * PP];
        const float sub = (k0 == k) ? 1.0f : 0.0f;   // k >= 1 always here
        const float npos = n - sub;
        t = (npos > 0.0f) ? (kl / ((float)CC * fmaxf(n, 1.0f))) : 0.0f;
    }
    partial[tid] = t;
    __syncthreads();
    for (int s = 64; s > 0; s >>= 1) {
        if (tid < s) partial[tid] += partial[tid + s];
        __syncthreads();
    }
    if (tid == 0) out[0] = partial[0];  // LOSS_WEIGHT * TAU^2 = 1
}

extern "C" void kernel_launch(void* const* d_in, const int* in_sizes, int n_in,
                              void* d_out, int out_size, void* d_ws, size_t ws_size,
                              hipStream_t stream) {
    const float* S  = (const float*)d_in[0];
    const float* T  = (const float*)d_in[1];
    const int*   gt = (const int*)d_in[2];
    float* out = (float*)d_out;
    float* ws  = (float*)d_ws;

    hipLaunchKernelGGL(zero_ws_kernel, dim3(1), dim3(256), 0, stream, ws);
    hipLaunchKernelGGL(boundary_kl_kernel, dim3(BB * BLOCKS_PER_IMG), dim3(256), 0, stream,
                       S, T, gt, ws);
    hipLaunchKernelGGL(finalize_kernel, dim3(1), dim3(128), 0, stream, ws, gt, out);
}